// Round 1
// baseline (101.617 us; speedup 1.0000x reference)
//
#include <hip/hip_runtime.h>

// Phase 1: per-node dot products s[n] = x[n]·att[0:128], t[n] = x[n]·att[128:256]
// One wave handles a pair of nodes (256 contiguous floats = 64 lanes × float4).
// v2: grid-strided persistent waves, 4 independent pair-loads in flight per wave
// (4 KB/wave MLP instead of 1 KB/wave-lifetime) to reach HBM bandwidth instead of
// being wave-churn/latency bound.

__device__ __forceinline__ float dot4(float4 a, float4 b) {
  return a.x * b.x + a.y * b.y + a.z * b.z + a.w * b.w;
}

// Half-wave (32-lane) tree reduction; shfl_down over the full 64-lane wave is
// still exact for each half because reads precede writes at every level
// (lane 0 accumulates exactly lanes 0..31, lane 32 exactly lanes 32..63).
__device__ __forceinline__ void reduce_store(float ps, float pt, int pair, int lane,
                                             float* __restrict__ s,
                                             float* __restrict__ t) {
  #pragma unroll
  for (int off = 16; off; off >>= 1) {
    ps += __shfl_down(ps, off);
    pt += __shfl_down(pt, off);
  }
  if ((lane & 31) == 0) {
    int n = 2 * pair + (lane >> 5);
    s[n] = ps;
    t[n] = pt;
  }
}

__global__ __launch_bounds__(256) void node_dots_kernel(
    const float* __restrict__ x, const float* __restrict__ att,
    float* __restrict__ s, float* __restrict__ t, int n_pairs) {
  const int lane = threadIdx.x & 63;
  const int wave = (blockIdx.x * blockDim.x + threadIdx.x) >> 6;
  const int n_waves = (gridDim.x * blockDim.x) >> 6;
  const int wl = lane & 31;

  // att is 1 KB; loaded once per wave, L1-resident.
  const float4* a4 = (const float4*)att;
  const float4 ws = a4[wl];        // att[0:128]   (w_src)
  const float4 wt = a4[32 + wl];   // att[128:256] (w_tgt)
  const float4* xb = (const float4*)x;

  int i = wave;
  // Main loop: 4 independent 1 KB wave-loads issued before any reduction.
  for (; i + 3 * n_waves < n_pairs; i += 4 * n_waves) {
    const int i0 = i;
    const int i1 = i + n_waves;
    const int i2 = i + 2 * n_waves;
    const int i3 = i + 3 * n_waves;
    float4 v0 = xb[(size_t)i0 * 64 + lane];
    float4 v1 = xb[(size_t)i1 * 64 + lane];
    float4 v2 = xb[(size_t)i2 * 64 + lane];
    float4 v3 = xb[(size_t)i3 * 64 + lane];
    float ps0 = dot4(v0, ws), pt0 = dot4(v0, wt);
    float ps1 = dot4(v1, ws), pt1 = dot4(v1, wt);
    float ps2 = dot4(v2, ws), pt2 = dot4(v2, wt);
    float ps3 = dot4(v3, ws), pt3 = dot4(v3, wt);
    // Four independent shuffle chains — scheduler interleaves them.
    reduce_store(ps0, pt0, i0, lane, s, t);
    reduce_store(ps1, pt1, i1, lane, s, t);
    reduce_store(ps2, pt2, i2, lane, s, t);
    reduce_store(ps3, pt3, i3, lane, s, t);
  }
  // Tail.
  for (; i < n_pairs; i += n_waves) {
    float4 v = xb[(size_t)i * 64 + lane];
    reduce_store(dot4(v, ws), dot4(v, wt), i, lane, s, t);
  }
}

// Phase 2: out[e] = relu(s[src[e]] + t[tgt[e]])
// v2: 4 edges per thread — int4 index loads, 8 independent L2 gathers in
// flight, float4 output store. s/t total 800 KB -> L2-resident.
__global__ __launch_bounds__(256) void edge_signal_kernel(
    const int* __restrict__ src, const int* __restrict__ tgt,
    const float* __restrict__ s, const float* __restrict__ t,
    float* __restrict__ out, int n_edges) {
  int q = blockIdx.x * blockDim.x + threadIdx.x;
  int n_quads = n_edges >> 2;
  if (q < n_quads) {
    int4 sv = ((const int4*)src)[q];
    int4 tv = ((const int4*)tgt)[q];
    float a = s[sv.x] + t[tv.x];
    float b = s[sv.y] + t[tv.y];
    float c = s[sv.z] + t[tv.z];
    float d = s[sv.w] + t[tv.w];
    float4 r;
    r.x = fmaxf(a, 0.0f);
    r.y = fmaxf(b, 0.0f);
    r.z = fmaxf(c, 0.0f);
    r.w = fmaxf(d, 0.0f);
    ((float4*)out)[q] = r;
  } else if (q == n_quads) {
    // Scalar tail (n_edges % 4 != 0); single thread, ≤3 edges.
    for (int e = n_quads * 4; e < n_edges; ++e) {
      float v = s[src[e]] + t[tgt[e]];
      out[e] = fmaxf(v, 0.0f);
    }
  }
}

extern "C" void kernel_launch(void* const* d_in, const int* in_sizes, int n_in,
                              void* d_out, int out_size, void* d_ws, size_t ws_size,
                              hipStream_t stream) {
  const float* x_0 = (const float*)d_in[0];
  const int*   src = (const int*)d_in[1];
  const int*   tgt = (const int*)d_in[2];
  const float* att = (const float*)d_in[3];
  float* out = (float*)d_out;

  const int C = 128;
  int n_nodes = in_sizes[0] / C;   // 100000
  int n_edges = in_sizes[1];       // 800000

  float* s = (float*)d_ws;         // n_nodes floats
  float* t = s + n_nodes;          // n_nodes floats

  int n_pairs = (n_nodes + 1) / 2; // 2 nodes per wave
  // 1024 blocks × 4 waves = 4096 waves; ~12 pairs/wave grid-stride.
  int grid1 = 1024;
  int max_grid1 = (n_pairs + 3) / 4;   // 4 waves per block
  if (grid1 > max_grid1) grid1 = max_grid1;
  node_dots_kernel<<<grid1, 256, 0, stream>>>(x_0, att, s, t, n_pairs);

  int n_quads = n_edges >> 2;
  int work2 = n_quads + ((n_edges & 3) ? 1 : 0);
  if (work2 == 0) work2 = 1;
  int grid2 = (work2 + 255) / 256;
  edge_signal_kernel<<<grid2, 256, 0, stream>>>(src, tgt, s, t, out, n_edges);
}